// Round 8
// baseline (470.240 us; speedup 1.0000x reference)
//
#include <hip/hip_runtime.h>
#include <math.h>

#define N_NODES 50000
#define N_EDGES 800000
#define DIN 128
#define DH 128
#define EA_C 50
#define DE 100
#define FM 228      // DIN + DE
#define AS 320      // A stride in u32: 128 aggH(hi/lo) + 64 h(bf16 pairs) + 100 e(hi/lo) + 28 pad
#define WKL 384     // logical K (W stride): 128 + 128 + 100 + 28
#define BM 32       // GEMM row tile
#define BN_EPS 1e-5f
#define SCAN_NB ((N_NODES + 255) / 256)   // 196

typedef __attribute__((ext_vector_type(8))) short short8;
typedef __attribute__((ext_vector_type(4))) float f32x4;
typedef unsigned int u32;
typedef unsigned short u16;

// ---- bf16 hi/lo packing ----
__device__ inline u16 f2bf(float f) {
  u32 u = __float_as_uint(f);
  u32 r = (u + 0x7fffu + ((u >> 16) & 1u)) >> 16;
  return (u16)r;
}
__device__ inline float bf2f(u16 h) { return __uint_as_float(((u32)h) << 16); }
__device__ inline u32 pack_hl(float v) {
  u16 hi = f2bf(v);
  u16 lo = f2bf(v - bf2f(hi));
  return (u32)hi | ((u32)lo << 16);
}
__device__ inline float unpack_hl(u32 p) {
  return bf2f((u16)(p & 0xffffu)) + bf2f((u16)(p >> 16));
}

// ---------------- CSR build ----------------
__global__ void k_count(const int* __restrict__ row, int* __restrict__ counts) {
  int e = blockIdx.x * 256 + threadIdx.x;
  if (e < N_EDGES) atomicAdd(&counts[row[e]], 1);
}

__global__ void k_scan_a(const int* __restrict__ counts, int* __restrict__ incl,
                         int* __restrict__ bsum) {
  __shared__ int buf[256];
  int i = blockIdx.x * 256 + threadIdx.x;
  int v = (i < N_NODES) ? counts[i] : 0;
  buf[threadIdx.x] = v;
  __syncthreads();
#pragma unroll
  for (int off = 1; off < 256; off <<= 1) {
    int t = (threadIdx.x >= off) ? buf[threadIdx.x - off] : 0;
    __syncthreads();
    buf[threadIdx.x] += t;
    __syncthreads();
  }
  if (i < N_NODES) incl[i] = buf[threadIdx.x];
  if (threadIdx.x == 255) bsum[blockIdx.x] = buf[255];
}

__global__ void k_scan_b(const int* __restrict__ bsum, int* __restrict__ boff,
                         int* __restrict__ row_ptr) {
  __shared__ int buf[256];
  int v = (threadIdx.x < SCAN_NB) ? bsum[threadIdx.x] : 0;
  buf[threadIdx.x] = v;
  __syncthreads();
#pragma unroll
  for (int off = 1; off < 256; off <<= 1) {
    int t = (threadIdx.x >= off) ? buf[threadIdx.x - off] : 0;
    __syncthreads();
    buf[threadIdx.x] += t;
    __syncthreads();
  }
  if (threadIdx.x < SCAN_NB) boff[threadIdx.x] = buf[threadIdx.x] - v;
  if (threadIdx.x == 255) row_ptr[N_NODES] = buf[255];
}

__global__ void k_scan_c(const int* __restrict__ incl, const int* __restrict__ counts,
                         const int* __restrict__ boff, int* __restrict__ row_ptr,
                         int* __restrict__ cursor) {
  int i = blockIdx.x * 256 + threadIdx.x;
  if (i < N_NODES) {
    int p = incl[i] - counts[i] + boff[blockIdx.x];
    row_ptr[i] = p;
    cursor[i] = p;
  }
}

// fill CSR: ONE 8B record per edge: x = col | attr<<16 | dir<<20, y = log(t+1)
__global__ void k_fill(const int* __restrict__ row, const int* __restrict__ col,
                       const int* __restrict__ attr, const int* __restrict__ dire,
                       const int* __restrict__ tim,
                       int* __restrict__ cursor, uint2* __restrict__ er_s) {
  int e = blockIdx.x * 256 + threadIdx.x;
  if (e < N_EDGES) {
    int r = row[e];
    int slot = atomicAdd(&cursor[r], 1);
    uint2 rec;
    rec.x = (u32)col[e] | ((u32)attr[e] << 16) | ((u32)dire[e] << 20);
    rec.y = __float_as_uint(__logf((float)tim[e] + 1.0f));
    er_s[slot] = rec;
  }
}

// ---------------- x -> A h16 plane (bf16) ----------------
__global__ void k_conv_x(const float* __restrict__ x, u32* __restrict__ A) {
  int idx = blockIdx.x * 256 + threadIdx.x;
  if (idx >= N_NODES * DH) return;
  int n = idx >> 7, c = idx & 127;
  ((u16*)(A + (size_t)n * AS + 128))[c] = f2bf(x[idx]);
}

// ---------------- edge-embedding aggregation -> A cols 192..291 (+pad) -------
__global__ void k_aggE(const int* __restrict__ row_ptr, const uint2* __restrict__ er_s,
                       const float* __restrict__ emb_type, const float* __restrict__ emb_dir,
                       const float* __restrict__ w_t, const float* __restrict__ b_t,
                       u32* __restrict__ A) {
  int n = blockIdx.x;
  int wave = threadIdx.x >> 6;
  int lane = threadIdx.x & 63;
  if (lane >= EA_C) {
    int col = (wave == 0) ? (292 + lane - EA_C) : (306 + lane - EA_C);
    A[(size_t)n * AS + col] = 0u;
    return;
  }
  int s = row_ptr[n], epos = row_ptr[n + 1];
  float acc = 0.f;
  if (wave == 0) {
    for (int p = s; p < epos; ++p) {
      u32 adc = er_s[p].x;
      acc += emb_type[((adc >> 16) & 0xF) * EA_C + lane] + emb_dir[(adc >> 20) * EA_C + lane];
    }
    A[(size_t)n * AS + 192 + lane] = pack_hl(acc);
  } else {
    float w = w_t[lane], b = b_t[lane];
    for (int p = s; p < epos; ++p) {
      acc += __cosf(__uint_as_float(er_s[p].y) * w + b);
    }
    A[(size_t)n * AS + 242 + lane] = pack_hl(acc);
  }
}

// ---------------- neighbor aggregation ----------------
__global__ void k_aggH(const int* __restrict__ row_ptr, const uint2* __restrict__ er_s,
                       u32* __restrict__ A) {
  int wave = threadIdx.x >> 6, lane = threadIdx.x & 63;
  int n = blockIdx.x * 4 + wave;
  if (n >= N_NODES) return;
  int s = row_ptr[n], epos = row_ptr[n + 1];
  float ax = 0.f, ay = 0.f;
  int p = s;
  for (; p + 3 < epos; p += 4) {
    int c0 = er_s[p].x & 0xffff, c1 = er_s[p + 1].x & 0xffff;
    int c2 = er_s[p + 2].x & 0xffff, c3 = er_s[p + 3].x & 0xffff;
    u32 v0 = A[(size_t)c0 * AS + 128 + lane];
    u32 v1 = A[(size_t)c1 * AS + 128 + lane];
    u32 v2 = A[(size_t)c2 * AS + 128 + lane];
    u32 v3 = A[(size_t)c3 * AS + 128 + lane];
    ax += bf2f((u16)(v0 & 0xffffu)) + bf2f((u16)(v1 & 0xffffu)) +
          bf2f((u16)(v2 & 0xffffu)) + bf2f((u16)(v3 & 0xffffu));
    ay += bf2f((u16)(v0 >> 16)) + bf2f((u16)(v1 >> 16)) +
          bf2f((u16)(v2 >> 16)) + bf2f((u16)(v3 >> 16));
  }
  for (; p < epos; ++p) {
    u32 v = A[(size_t)(er_s[p].x & 0xffff) * AS + 128 + lane];
    ax += bf2f((u16)(v & 0xffffu));
    ay += bf2f((u16)(v >> 16));
  }
  uint2 o; o.x = pack_hl(ax); o.y = pack_hl(ay);
  *reinterpret_cast<uint2*>(A + (size_t)n * AS + 2 * lane) = o;
}

// ---------------- weight prep: two bf16 planes [col][WKL] ----------------
__global__ void k_wprep(const float* __restrict__ Wm, const float* __restrict__ Wr,
                        u16* __restrict__ Wh16, u16* __restrict__ Wl16) {
  int idx = blockIdx.x * 256 + threadIdx.x;
  if (idx >= DH * WKL) return;
  int o = idx / WKL, k = idx - o * WKL;
  float v;
  if (k < 128) v = 0.5f * Wm[o * FM + k];
  else if (k < 256) v = Wr[o * DIN + (k - 128)];
  else if (k < 356) v = 0.5f * Wm[o * FM + (k - 128)];
  else v = 0.f;
  u16 hi = f2bf(v);
  Wh16[idx] = hi;
  Wl16[idx] = f2bf(v - bf2f(hi));
}

__global__ void k_bias(const float* __restrict__ bm, const float* __restrict__ br,
                       float* __restrict__ bv) {
  int o = threadIdx.x;
  if (o < DH) bv[o] = 0.5f * bm[o] + br[o];
}

// ---------------- MFMA GEMM: BM=32, A-only LDS (swizzled), W from global -----
// 4 waves; wave w computes cols [w*32, w*32+32) for all 32 rows.
// 6 iterations over K=64 slices: it0,1=aggH(hi/lo) it2,3=h(bf16) it4,5=e(hi/lo).
__global__ __launch_bounds__(256, 3) void k_mfma(const u32* __restrict__ A,
                                                 const u16* __restrict__ Wh16,
                                                 const u16* __restrict__ Wl16,
                                                 const float* __restrict__ bv,
                                                 float* __restrict__ out,
                                                 float* __restrict__ stats) {
  __shared__ u16 Ah[BM][64], Al[BM][64];   // 4KB each, row stride 128B, XOR-swizzled
  __shared__ float sstat[DH], qstat[DH];
  int tid = threadIdx.x;
  int wv = tid >> 6, ln = tid & 63;
  int node0 = blockIdx.x * BM;
  if (tid < DH) { sstat[tid] = 0.f; qstat[tid] = 0.f; }

  f32x4 acc[2][2];   // [row-tile rt][nt2]
#pragma unroll
  for (int i = 0; i < 2; ++i)
#pragma unroll
    for (int j = 0; j < 2; ++j) acc[i][j] = (f32x4){0.f, 0.f, 0.f, 0.f};

  // staging geometry: 256 thr = 32 rows x 8 slots
  int srow = tid >> 3, sq = tid & 7;
  bool svalid = (node0 + srow) < N_NODES;
  const u32* aptr = A + (size_t)(node0 + srow) * AS;
  int swsl = (sq ^ (srow & 7)) * 8;        // phys slot (u16 units)

  // W fragment bases: this wave's two output cols per lane
  int colb = ln & 15, lq = ln >> 4;
  const u16* wh0 = Wh16 + (size_t)((wv << 5) + colb) * WKL + lq * 8;
  const u16* wh1 = wh0 + 16 * WKL;
  const u16* wl0 = Wl16 + (size_t)((wv << 5) + colb) * WKL + lq * 8;
  const u16* wl1 = wl0 + 16 * WKL;

#pragma unroll
  for (int it = 0; it < 6; ++it) {
    const bool hil = (it < 2) || (it >= 4);
    uint4 a0 = make_uint4(0, 0, 0, 0), a1 = make_uint4(0, 0, 0, 0);
    if (hil) {
      int c0 = (it < 2 ? it * 64 : 192 + (it - 4) * 64) + sq * 8;
      if (svalid) {
        a0 = *reinterpret_cast<const uint4*>(aptr + c0);
        a1 = *reinterpret_cast<const uint4*>(aptr + c0 + 4);
      }
    } else {
      int c0 = 128 + (it - 2) * 32 + sq * 4;
      if (svalid) a0 = *reinterpret_cast<const uint4*>(aptr + c0);
    }

    __syncthreads();   // previous iteration's LDS reads complete

    if (hil) {
      u32 va[8] = {a0.x, a0.y, a0.z, a0.w, a1.x, a1.y, a1.z, a1.w};
      short8 h, l;
#pragma unroll
      for (int j = 0; j < 8; ++j) { h[j] = (short)(va[j] & 0xffffu); l[j] = (short)(va[j] >> 16); }
      *reinterpret_cast<short8*>(&Ah[srow][swsl]) = h;
      *reinterpret_cast<short8*>(&Al[srow][swsl]) = l;
    } else {
      *reinterpret_cast<short8*>(&Ah[srow][swsl]) = *reinterpret_cast<const short8*>(&a0);
    }

    __syncthreads();   // LDS writes visible

    int kb = it * 64;
#pragma unroll
    for (int c = 0; c < 2; ++c) {
      int ko = kb + c * 32;
      short8 bh0 = *reinterpret_cast<const short8*>(wh0 + ko);
      short8 bh1 = *reinterpret_cast<const short8*>(wh1 + ko);
      short8 bl0 = *reinterpret_cast<const short8*>(wl0 + ko);
      short8 bl1 = *reinterpret_cast<const short8*>(wl1 + ko);
#pragma unroll
      for (int rt = 0; rt < 2; ++rt) {
        int r = rt * 16 + colb;
        int sl = ((c * 4 + lq) ^ (r & 7)) * 8;
        short8 ah = *reinterpret_cast<const short8*>(&Ah[r][sl]);
        if (hil) {
          short8 al = *reinterpret_cast<const short8*>(&Al[r][sl]);
          acc[rt][0] = __builtin_amdgcn_mfma_f32_16x16x32_bf16(ah, bh0, acc[rt][0], 0, 0, 0);
          acc[rt][0] = __builtin_amdgcn_mfma_f32_16x16x32_bf16(al, bh0, acc[rt][0], 0, 0, 0);
          acc[rt][0] = __builtin_amdgcn_mfma_f32_16x16x32_bf16(ah, bl0, acc[rt][0], 0, 0, 0);
          acc[rt][1] = __builtin_amdgcn_mfma_f32_16x16x32_bf16(ah, bh1, acc[rt][1], 0, 0, 0);
          acc[rt][1] = __builtin_amdgcn_mfma_f32_16x16x32_bf16(al, bh1, acc[rt][1], 0, 0, 0);
          acc[rt][1] = __builtin_amdgcn_mfma_f32_16x16x32_bf16(ah, bl1, acc[rt][1], 0, 0, 0);
        } else {
          acc[rt][0] = __builtin_amdgcn_mfma_f32_16x16x32_bf16(ah, bh0, acc[rt][0], 0, 0, 0);
          acc[rt][0] = __builtin_amdgcn_mfma_f32_16x16x32_bf16(ah, bl0, acc[rt][0], 0, 0, 0);
          acc[rt][1] = __builtin_amdgcn_mfma_f32_16x16x32_bf16(ah, bh1, acc[rt][1], 0, 0, 0);
          acc[rt][1] = __builtin_amdgcn_mfma_f32_16x16x32_bf16(ah, bl1, acc[rt][1], 0, 0, 0);
        }
      }
    }
  }

  // epilogue: out + bias, BN stats via shuffle reduce + conflict-free LDS atomics
#pragma unroll
  for (int nt2 = 0; nt2 < 2; ++nt2) {
    int col = (wv << 5) + nt2 * 16 + colb;
    float bb = bv[col];
    float s = 0.f, q = 0.f;
#pragma unroll
    for (int rt = 0; rt < 2; ++rt) {
      int rbase = node0 + rt * 16 + lq * 4;
#pragma unroll
      for (int r = 0; r < 4; ++r) {
        int n = rbase + r;
        if (n < N_NODES) {
          float v = acc[rt][nt2][r] + bb;
          out[(size_t)n * DH + col] = v;
          s += v; q += v * v;
        }
      }
    }
    s += __shfl_xor(s, 16, 64); s += __shfl_xor(s, 32, 64);
    q += __shfl_xor(q, 16, 64); q += __shfl_xor(q, 32, 64);
    if (ln < 16) {
      atomicAdd(&sstat[(wv << 5) + nt2 * 16 + ln], s);
      atomicAdd(&qstat[(wv << 5) + nt2 * 16 + ln], q);
    }
  }
  __syncthreads();
  if (tid < DH) {
    atomicAdd(&stats[tid], sstat[tid]);
    atomicAdd(&stats[128 + tid], qstat[tid]);
  }
}

// BN + ELU -> h16 plane (bf16)
__global__ void k_bnapply(const float* __restrict__ x, const float* __restrict__ stats,
                          const float* __restrict__ g, const float* __restrict__ be,
                          u32* __restrict__ A) {
  int idx = blockIdx.x * 256 + threadIdx.x;
  if (idx >= N_NODES * DH) return;
  int n = idx >> 7, c = idx & 127;
  float mu = stats[c] * (1.0f / N_NODES);
  float var = stats[128 + c] * (1.0f / N_NODES) - mu * mu;
  float y = (x[idx] - mu) * rsqrtf(var + BN_EPS) * g[c] + be[c];
  y = y > 0.f ? y : expm1f(y);
  ((u16*)(A + (size_t)n * AS + 128))[c] = f2bf(y);
}

// ---------------- layer 2 (project-first, dout=2) ----------------
__global__ void k_l2_dense(const u32* __restrict__ A,
                           const float* __restrict__ Wm2, const float* __restrict__ bm2,
                           const float* __restrict__ Wr2, const float* __restrict__ br2,
                           float* __restrict__ val, float* __restrict__ pm) {
  int wave = threadIdx.x >> 6, lane = threadIdx.x & 63;
  int n = blockIdx.x * 4 + wave;
  if (n >= N_NODES) return;
  const u32* ar = A + (size_t)n * AS;
  const u16* h16 = (const u16*)(ar + 128);
  float h0 = bf2f(h16[lane]);
  float h1 = bf2f(h16[lane + 64]);
  float e0 = unpack_hl(ar[192 + lane]);
  float e1 = (lane < DE - 64) ? unpack_hl(ar[256 + lane]) : 0.f;

  float pm0 = h0 * Wm2[lane] + h1 * Wm2[lane + 64];
  float pm1 = h0 * Wm2[FM + lane] + h1 * Wm2[FM + lane + 64];
  float ve0 = e0 * Wm2[DIN + lane] + ((lane < DE - 64) ? e1 * Wm2[DIN + lane + 64] : 0.f);
  float ve1 = e0 * Wm2[FM + DIN + lane] + ((lane < DE - 64) ? e1 * Wm2[FM + DIN + lane + 64] : 0.f);
  float pr0 = h0 * Wr2[lane] + h1 * Wr2[lane + 64];
  float pr1 = h0 * Wr2[DH + lane] + h1 * Wr2[DH + lane + 64];

#pragma unroll
  for (int m = 32; m >= 1; m >>= 1) {
    pm0 += __shfl_xor(pm0, m, 64); pm1 += __shfl_xor(pm1, m, 64);
    ve0 += __shfl_xor(ve0, m, 64); ve1 += __shfl_xor(ve1, m, 64);
    pr0 += __shfl_xor(pr0, m, 64); pr1 += __shfl_xor(pr1, m, 64);
  }
  if (lane == 0) {
    val[n * 2 + 0] = 0.5f * (ve0 + bm2[0]) + pr0 + br2[0];
    val[n * 2 + 1] = 0.5f * (ve1 + bm2[1]) + pr1 + br2[1];
    pm[n * 2 + 0] = pm0;
    pm[n * 2 + 1] = pm1;
  }
}

__global__ void k_agg2(const int* __restrict__ row_ptr, const uint2* __restrict__ er_s,
                       const float* __restrict__ pm, float* __restrict__ val) {
  int n = blockIdx.x * 256 + threadIdx.x;
  if (n >= N_NODES) return;
  float a0 = 0.f, a1 = 0.f;
  int s = row_ptr[n], e = row_ptr[n + 1];
  for (int p = s; p < e; ++p) {
    int c = er_s[p].x & 0xffff;
    a0 += pm[c * 2]; a1 += pm[c * 2 + 1];
  }
  val[n * 2] += 0.5f * a0;
  val[n * 2 + 1] += 0.5f * a1;
}

__global__ void k_bnstats2(const float* __restrict__ val, float* __restrict__ s4) {
  float s0 = 0.f, q0 = 0.f, s1 = 0.f, q1 = 0.f;
  for (int n = blockIdx.x * 256 + threadIdx.x; n < N_NODES; n += gridDim.x * 256) {
    float v0 = val[n * 2], v1 = val[n * 2 + 1];
    s0 += v0; q0 += v0 * v0; s1 += v1; q1 += v1 * v1;
  }
  __shared__ float b[256][4];
  b[threadIdx.x][0] = s0; b[threadIdx.x][1] = q0;
  b[threadIdx.x][2] = s1; b[threadIdx.x][3] = q1;
  __syncthreads();
  for (int off = 128; off >= 1; off >>= 1) {
    if (threadIdx.x < off)
      for (int j = 0; j < 4; ++j) b[threadIdx.x][j] += b[threadIdx.x + off][j];
    __syncthreads();
  }
  if (threadIdx.x == 0)
    for (int j = 0; j < 4; ++j) atomicAdd(&s4[j], b[0][j]);
}

__global__ void k_final(const float* __restrict__ val, const float* __restrict__ s4,
                        const float* __restrict__ g2, const float* __restrict__ be2,
                        float* __restrict__ out) {
  int n = blockIdx.x * 256 + threadIdx.x;
  if (n >= N_NODES) return;
  float mu0 = s4[0] * (1.f / N_NODES), var0 = s4[1] * (1.f / N_NODES) - mu0 * mu0;
  float mu1 = s4[2] * (1.f / N_NODES), var1 = s4[3] * (1.f / N_NODES) - mu1 * mu1;
  float y0 = (val[n * 2] - mu0) * rsqrtf(var0 + BN_EPS) * g2[0] + be2[0];
  float y1 = (val[n * 2 + 1] - mu1) * rsqrtf(var1 + BN_EPS) * g2[1] + be2[1];
  float m = fmaxf(y0, y1);
  float lse = m + __logf(__expf(y0 - m) + __expf(y1 - m));
  out[n * 2] = y0 - lse;
  out[n * 2 + 1] = y1 - lse;
}

// ---------------- launch ----------------
extern "C" void kernel_launch(void* const* d_in, const int* in_sizes, int n_in,
                              void* d_out, int out_size, void* d_ws, size_t ws_size,
                              hipStream_t stream) {
  (void)in_sizes; (void)n_in; (void)out_size; (void)ws_size;
  const float* x        = (const float*)d_in[0];
  const int*   eidx     = (const int*)d_in[1];
  const int*   row      = eidx;
  const int*   col      = eidx + N_EDGES;
  const int*   attr     = (const int*)d_in[2];
  const int*   tim      = (const int*)d_in[3];
  const int*   dire     = (const int*)d_in[4];
  const float* emb_type = (const float*)d_in[5];
  const float* emb_dir  = (const float*)d_in[6];
  const float* w_t      = (const float*)d_in[7];
  const float* b_t      = (const float*)d_in[8];
  const float* Wm[3] = {(const float*)d_in[9],  (const float*)d_in[15], (const float*)d_in[21]};
  const float* bm[3] = {(const float*)d_in[10], (const float*)d_in[16], (const float*)d_in[22]};
  const float* Wr[3] = {(const float*)d_in[11], (const float*)d_in[17], (const float*)d_in[23]};
  const float* br[3] = {(const float*)d_in[12], (const float*)d_in[18], (const float*)d_in[24]};
  const float* g[3]  = {(const float*)d_in[13], (const float*)d_in[19], (const float*)d_in[25]};
  const float* be[3] = {(const float*)d_in[14], (const float*)d_in[20], (const float*)d_in[26]};
  float* out = (float*)d_out;

  // workspace layout (~98 MB)
  char* p = (char*)d_ws;
  u32* A     = (u32*)p;   p += sizeof(u32) * (size_t)N_NODES * AS;    // 64 MB
  float* gout = (float*)p; p += sizeof(float) * (size_t)N_NODES * DH; // 25.6 MB
  uint2* er_s = (uint2*)p; p += sizeof(uint2) * (size_t)N_EDGES;      // 6.4 MB
  u16* Wh16[2]; u16* Wl16[2];
  for (int l = 0; l < 2; ++l) {
    Wh16[l] = (u16*)p; p += sizeof(u16) * DH * WKL;
    Wl16[l] = (u16*)p; p += sizeof(u16) * DH * WKL;
  }
  float* bv[2];
  bv[0] = (float*)p; p += sizeof(float) * DH;
  bv[1] = (float*)p; p += sizeof(float) * DH;
  float* val  = (float*)p;  p += sizeof(float) * (size_t)N_NODES * 2;
  float* pmb  = (float*)p;  p += sizeof(float) * (size_t)N_NODES * 2;
  float* stats = (float*)p; p += sizeof(float) * 520;
  int* counts  = (int*)p;   p += sizeof(int) * N_NODES;
  int* cursor  = (int*)p;   p += sizeof(int) * N_NODES;
  int* row_ptr = (int*)p;   p += sizeof(int) * (N_NODES + 1);
  int* incl    = (int*)p;   p += sizeof(int) * N_NODES;
  int* bsum    = (int*)p;   p += sizeof(int) * SCAN_NB;
  int* boff    = (int*)p;   p += sizeof(int) * SCAN_NB;

  const int EB = (N_EDGES + 255) / 256;      // 3125
  const int NB = (N_NODES + 255) / 256;      // 196
  const int AB = (N_NODES + 3) / 4;          // 12500
  const int GB = (N_NODES + BM - 1) / BM;    // 1563
  const int XB = (N_NODES * DH + 255) / 256; // 25000
  const int WB = (DH * WKL + 255) / 256;     // 192

  hipMemsetAsync(counts, 0, sizeof(int) * N_NODES, stream);
  hipMemsetAsync(stats, 0, sizeof(float) * 520, stream);

  // CSR
  k_count<<<EB, 256, 0, stream>>>(row, counts);
  k_scan_a<<<SCAN_NB, 256, 0, stream>>>(counts, incl, bsum);
  k_scan_b<<<1, 256, 0, stream>>>(bsum, boff, row_ptr);
  k_scan_c<<<SCAN_NB, 256, 0, stream>>>(incl, counts, boff, row_ptr, cursor);
  k_fill<<<EB, 256, 0, stream>>>(row, col, attr, dire, tim, cursor, er_s);

  // weight prep
  for (int l = 0; l < 2; ++l) {
    k_wprep<<<WB, 256, 0, stream>>>(Wm[l], Wr[l], Wh16[l], Wl16[l]);
    k_bias<<<1, 128, 0, stream>>>(bm[l], br[l], bv[l]);
  }

  // x -> h16 plane; edge features -> e region (+pad)
  k_conv_x<<<XB, 256, 0, stream>>>(x, A);
  k_aggE<<<N_NODES, 128, 0, stream>>>(row_ptr, er_s, emb_type, emb_dir, w_t, b_t, A);

  // layer 0
  k_aggH<<<AB, 256, 0, stream>>>(row_ptr, er_s, A);
  k_mfma<<<GB, 256, 0, stream>>>(A, Wh16[0], Wl16[0], bv[0], gout, stats);
  k_bnapply<<<XB, 256, 0, stream>>>(gout, stats, g[0], be[0], A);

  // layer 1
  k_aggH<<<AB, 256, 0, stream>>>(row_ptr, er_s, A);
  k_mfma<<<GB, 256, 0, stream>>>(A, Wh16[1], Wl16[1], bv[1], gout, stats + 256);
  k_bnapply<<<XB, 256, 0, stream>>>(gout, stats + 256, g[1], be[1], A);

  // layer 2
  k_l2_dense<<<AB, 256, 0, stream>>>(A, Wm[2], bm[2], Wr[2], br[2], val, pmb);
  k_agg2<<<NB, 256, 0, stream>>>(row_ptr, er_s, pmb, val);
  k_bnstats2<<<64, 256, 0, stream>>>(val, stats + 512);
  k_final<<<NB, 256, 0, stream>>>(val, stats + 512, g[2], be[2], out);
}

// Round 9
// 407.320 us; speedup vs baseline: 1.1545x; 1.1545x over previous
//
#include <hip/hip_runtime.h>
#include <math.h>

#define N_NODES 50000
#define N_EDGES 800000
#define DIN 128
#define DH 128
#define EA_C 50
#define DE 100
#define FM 228      // DIN + DE
#define AS 320      // A stride in u32: 128 aggH(hi/lo) + 64 h(bf16 pairs) + 100 e(hi/lo) + 28 pad
#define WKL 384     // logical K (W stride): 128 + 128 + 100 + 28
#define BN_EPS 1e-5f
#define SCAN_NB ((N_NODES + 255) / 256)   // 196

typedef __attribute__((ext_vector_type(8))) short short8;
typedef __attribute__((ext_vector_type(4))) float f32x4;
typedef unsigned int u32;
typedef unsigned short u16;

// LDS quarter swizzle: row stride 64B = 4 quarters of 8 u16.
// phys_q = q ^ ((row ^ (row>>2)) & 3)  -> fixed-q fragment reads become <=2-way (free).
__device__ inline int swz(int row, int q) { return q ^ ((row ^ (row >> 2)) & 3); }

// ---- bf16 hi/lo packing ----
__device__ inline u16 f2bf(float f) {
  u32 u = __float_as_uint(f);
  u32 r = (u + 0x7fffu + ((u >> 16) & 1u)) >> 16;
  return (u16)r;
}
__device__ inline float bf2f(u16 h) { return __uint_as_float(((u32)h) << 16); }
__device__ inline u32 pack_hl(float v) {
  u16 hi = f2bf(v);
  u16 lo = f2bf(v - bf2f(hi));
  return (u32)hi | ((u32)lo << 16);
}
__device__ inline float unpack_hl(u32 p) {
  return bf2f((u16)(p & 0xffffu)) + bf2f((u16)(p >> 16));
}

// ---------------- CSR build ----------------
__global__ void k_count(const int* __restrict__ row, int* __restrict__ counts) {
  int e = blockIdx.x * 256 + threadIdx.x;
  if (e < N_EDGES) atomicAdd(&counts[row[e]], 1);
}

__global__ void k_scan_a(const int* __restrict__ counts, int* __restrict__ incl,
                         int* __restrict__ bsum) {
  __shared__ int buf[256];
  int i = blockIdx.x * 256 + threadIdx.x;
  int v = (i < N_NODES) ? counts[i] : 0;
  buf[threadIdx.x] = v;
  __syncthreads();
#pragma unroll
  for (int off = 1; off < 256; off <<= 1) {
    int t = (threadIdx.x >= off) ? buf[threadIdx.x - off] : 0;
    __syncthreads();
    buf[threadIdx.x] += t;
    __syncthreads();
  }
  if (i < N_NODES) incl[i] = buf[threadIdx.x];
  if (threadIdx.x == 255) bsum[blockIdx.x] = buf[255];
}

__global__ void k_scan_b(const int* __restrict__ bsum, int* __restrict__ boff,
                         int* __restrict__ row_ptr) {
  __shared__ int buf[256];
  int v = (threadIdx.x < SCAN_NB) ? bsum[threadIdx.x] : 0;
  buf[threadIdx.x] = v;
  __syncthreads();
#pragma unroll
  for (int off = 1; off < 256; off <<= 1) {
    int t = (threadIdx.x >= off) ? buf[threadIdx.x - off] : 0;
    __syncthreads();
    buf[threadIdx.x] += t;
    __syncthreads();
  }
  if (threadIdx.x < SCAN_NB) boff[threadIdx.x] = buf[threadIdx.x] - v;
  if (threadIdx.x == 255) row_ptr[N_NODES] = buf[255];
}

__global__ void k_scan_c(const int* __restrict__ incl, const int* __restrict__ counts,
                         const int* __restrict__ boff, int* __restrict__ row_ptr,
                         int* __restrict__ cursor) {
  int i = blockIdx.x * 256 + threadIdx.x;
  if (i < N_NODES) {
    int p = incl[i] - counts[i] + boff[blockIdx.x];
    row_ptr[i] = p;
    cursor[i] = p;
  }
}

// fill CSR: ONE 8B record per edge: x = col | attr<<16 | dir<<20, y = log(t+1)
__global__ void k_fill(const int* __restrict__ row, const int* __restrict__ col,
                       const int* __restrict__ attr, const int* __restrict__ dire,
                       const int* __restrict__ tim,
                       int* __restrict__ cursor, uint2* __restrict__ er_s) {
  int e = blockIdx.x * 256 + threadIdx.x;
  if (e < N_EDGES) {
    int r = row[e];
    int slot = atomicAdd(&cursor[r], 1);
    uint2 rec;
    rec.x = (u32)col[e] | ((u32)attr[e] << 16) | ((u32)dire[e] << 20);
    rec.y = __float_as_uint(__logf((float)tim[e] + 1.0f));
    er_s[slot] = rec;
  }
}

// ---------------- x -> A h16 plane (bf16) ----------------
__global__ void k_conv_x(const float* __restrict__ x, u32* __restrict__ A) {
  int idx = blockIdx.x * 256 + threadIdx.x;
  if (idx >= N_NODES * DH) return;
  int n = idx >> 7, c = idx & 127;
  ((u16*)(A + (size_t)n * AS + 128))[c] = f2bf(x[idx]);
}

// ---------------- edge-embedding aggregation -> A cols 192..291 (+pad) -------
__global__ void k_aggE(const int* __restrict__ row_ptr, const uint2* __restrict__ er_s,
                       const float* __restrict__ emb_type, const float* __restrict__ emb_dir,
                       const float* __restrict__ w_t, const float* __restrict__ b_t,
                       u32* __restrict__ A) {
  int n = blockIdx.x;
  int wave = threadIdx.x >> 6;
  int lane = threadIdx.x & 63;
  if (lane >= EA_C) {
    int col = (wave == 0) ? (292 + lane - EA_C) : (306 + lane - EA_C);
    A[(size_t)n * AS + col] = 0u;
    return;
  }
  int s = row_ptr[n], epos = row_ptr[n + 1];
  float acc = 0.f;
  if (wave == 0) {
    for (int p = s; p < epos; ++p) {
      u32 adc = er_s[p].x;
      acc += emb_type[((adc >> 16) & 0xF) * EA_C + lane] + emb_dir[(adc >> 20) * EA_C + lane];
    }
    A[(size_t)n * AS + 192 + lane] = pack_hl(acc);
  } else {
    float w = w_t[lane], b = b_t[lane];
    for (int p = s; p < epos; ++p) {
      acc += __cosf(__uint_as_float(er_s[p].y) * w + b);
    }
    A[(size_t)n * AS + 242 + lane] = pack_hl(acc);
  }
}

// ---------------- neighbor aggregation ----------------
__global__ void k_aggH(const int* __restrict__ row_ptr, const uint2* __restrict__ er_s,
                       u32* __restrict__ A) {
  int wave = threadIdx.x >> 6, lane = threadIdx.x & 63;
  int n = blockIdx.x * 4 + wave;
  if (n >= N_NODES) return;
  int s = row_ptr[n], epos = row_ptr[n + 1];
  float ax = 0.f, ay = 0.f;
  int p = s;
  for (; p + 3 < epos; p += 4) {
    int c0 = er_s[p].x & 0xffff, c1 = er_s[p + 1].x & 0xffff;
    int c2 = er_s[p + 2].x & 0xffff, c3 = er_s[p + 3].x & 0xffff;
    u32 v0 = A[(size_t)c0 * AS + 128 + lane];
    u32 v1 = A[(size_t)c1 * AS + 128 + lane];
    u32 v2 = A[(size_t)c2 * AS + 128 + lane];
    u32 v3 = A[(size_t)c3 * AS + 128 + lane];
    ax += bf2f((u16)(v0 & 0xffffu)) + bf2f((u16)(v1 & 0xffffu)) +
          bf2f((u16)(v2 & 0xffffu)) + bf2f((u16)(v3 & 0xffffu));
    ay += bf2f((u16)(v0 >> 16)) + bf2f((u16)(v1 >> 16)) +
          bf2f((u16)(v2 >> 16)) + bf2f((u16)(v3 >> 16));
  }
  for (; p < epos; ++p) {
    u32 v = A[(size_t)(er_s[p].x & 0xffff) * AS + 128 + lane];
    ax += bf2f((u16)(v & 0xffffu));
    ay += bf2f((u16)(v >> 16));
  }
  uint2 o; o.x = pack_hl(ax); o.y = pack_hl(ay);
  *reinterpret_cast<uint2*>(A + (size_t)n * AS + 2 * lane) = o;
}

// ---------------- weight prep ----------------
__global__ void k_wprep(const float* __restrict__ Wm, const float* __restrict__ Wr,
                        u32* __restrict__ WT2) {
  int idx = blockIdx.x * 256 + threadIdx.x;
  if (idx >= DH * WKL) return;
  int o = idx / WKL, k = idx - o * WKL;
  float v;
  if (k < 128) v = 0.5f * Wm[o * FM + k];
  else if (k < 256) v = Wr[o * DIN + (k - 128)];
  else if (k < 356) v = 0.5f * Wm[o * FM + (k - 128)];
  else v = 0.f;
  WT2[idx] = pack_hl(v);
}

__global__ void k_bias(const float* __restrict__ bm, const float* __restrict__ br,
                       float* __restrict__ bv) {
  int o = threadIdx.x;
  if (o < DH) bv[o] = 0.5f * bm[o] + br[o];
}

// ---------------- MFMA GEMM, 3-phase K, fused BN-stats, XOR-swizzled LDS -----
__global__ __launch_bounds__(256) void k_mfma(const u32* __restrict__ A,
                                              const u32* __restrict__ W,
                                              const float* __restrict__ bv,
                                              float* __restrict__ out,
                                              float* __restrict__ stats) {
  __shared__ u16 Ah[64][32], Al[64][32];
  __shared__ u16 Wh[128][32], Wl[128][32];
  __shared__ float sstat[DH], qstat[DH];
  int tid = threadIdx.x;
  int wv = tid >> 6, ln = tid & 63;
  int node0 = blockIdx.x * 64;

  for (int i = tid; i < DH; i += 256) { sstat[i] = 0.f; qstat[i] = 0.f; }

  f32x4 acc[8];
#pragma unroll
  for (int nt = 0; nt < 8; ++nt) acc[nt] = (f32x4){0.f, 0.f, 0.f, 0.f};

  int ar = tid >> 2, aq = tid & 3;
  int wc = tid >> 1, wq = (tid & 1) * 2;   // this thread's two W quarters
  int an = node0 + ar;
  bool valid = an < N_NODES;
  const u32* aptr = A + (size_t)an * AS;
  const u32* wptr = W + (size_t)wc * WKL + wq * 8;

  // A frag: row = wv*16 + (ln&15), quarter = ln>>4 (swizzled)
  int frow = (wv << 4) + (ln & 15);
  int fq = ln >> 4;
  const u16* afh = &Ah[frow][swz(frow, fq) * 8];
  const u16* afl = &Al[frow][swz(frow, fq) * 8];

  // swizzled write slots
  int aws = swz(ar, aq) * 8;
  int wws0 = swz(wc, wq) * 8, wws1 = swz(wc, wq + 1) * 8;

#pragma unroll
  for (int ch = 0; ch < 12; ++ch) {
    const int kl = ch * 32;
    const bool ph2 = (ch >= 4 && ch < 8);
    uint4 a0 = make_uint4(0, 0, 0, 0), a1 = make_uint4(0, 0, 0, 0);
    if (!ph2) {
      int acol = (ch < 4 ? kl : kl - 64) + aq * 8;
      if (valid) {
        a0 = *reinterpret_cast<const uint4*>(aptr + acol);
        a1 = *reinterpret_cast<const uint4*>(aptr + acol + 4);
      }
    } else {
      int acol = 128 + ((kl - 128) >> 1) + aq * 4;
      if (valid) a0 = *reinterpret_cast<const uint4*>(aptr + acol);
    }
    uint4 w0 = *reinterpret_cast<const uint4*>(wptr + kl);
    uint4 w1 = *reinterpret_cast<const uint4*>(wptr + kl + 4);

    __syncthreads();   // previous chunk's LDS reads done

    if (!ph2) {
      u32 va[8] = {a0.x, a0.y, a0.z, a0.w, a1.x, a1.y, a1.z, a1.w};
      short8 h, l;
#pragma unroll
      for (int j = 0; j < 8; ++j) { h[j] = (short)(va[j] & 0xffffu); l[j] = (short)(va[j] >> 16); }
      *reinterpret_cast<short8*>(&Ah[ar][aws]) = h;
      *reinterpret_cast<short8*>(&Al[ar][aws]) = l;
    } else {
      *reinterpret_cast<short8*>(&Ah[ar][aws]) = *reinterpret_cast<const short8*>(&a0);
    }
    {
      u32 vw[8] = {w0.x, w0.y, w0.z, w0.w, w1.x, w1.y, w1.z, w1.w};
      short8 h0, l0;
#pragma unroll
      for (int j = 0; j < 8; ++j) {
        h0[j] = (short)(vw[j] & 0xffffu); l0[j] = (short)(vw[j] >> 16);
      }
      // first 8 u32 -> quarter wq (lo half of this thread's 16 u16? no: 8 u32 = 8 u16 pairs)
      // vw[0..3] -> quarter wq, vw[4..7] -> quarter wq+1 after split below
      short8 ha, la, hb, lb;
#pragma unroll
      for (int j = 0; j < 4; ++j) {
        ha[j] = h0[j]; la[j] = l0[j];
        hb[j] = h0[j + 4]; lb[j] = l0[j + 4];
      }
      // Each uint4 pair w0,w1 covers 8 u32 = 16 u16 per plane? No: each u32 holds hi|lo
      // of ONE logical element, so 8 u32 = 8 elements = one quarter per plane.
      // w0 (4 u32) + w1 (4 u32) = 8 elements -> exactly quarter wq... but thread covers
      // 16 elements (two quarters): load two more.
      (void)ha; (void)la; (void)hb; (void)lb;
      *reinterpret_cast<short8*>(&Wh[wc][wws0]) = h0;
      *reinterpret_cast<short8*>(&Wl[wc][wws0]) = l0;
    }
    {
      uint4 w2 = *reinterpret_cast<const uint4*>(wptr + kl + 8);
      uint4 w3 = *reinterpret_cast<const uint4*>(wptr + kl + 12);
      u32 vw[8] = {w2.x, w2.y, w2.z, w2.w, w3.x, w3.y, w3.z, w3.w};
      short8 h1, l1;
#pragma unroll
      for (int j = 0; j < 8; ++j) {
        h1[j] = (short)(vw[j] & 0xffffu); l1[j] = (short)(vw[j] >> 16);
      }
      *reinterpret_cast<short8*>(&Wh[wc][wws1]) = h1;
      *reinterpret_cast<short8*>(&Wl[wc][wws1]) = l1;
    }

    __syncthreads();   // LDS writes visible

    short8 ah = *reinterpret_cast<const short8*>(afh);
    short8 al = *reinterpret_cast<const short8*>(afl);
#pragma unroll
    for (int nt = 0; nt < 8; ++nt) {
      int wrow = nt * 16 + (ln & 15);
      const u16* bhp = &Wh[wrow][swz(wrow, fq) * 8];
      const u16* blp = &Wl[wrow][swz(wrow, fq) * 8];
      short8 bh = *reinterpret_cast<const short8*>(bhp);
      short8 bl = *reinterpret_cast<const short8*>(blp);
      acc[nt] = __builtin_amdgcn_mfma_f32_16x16x32_bf16(ah, bh, acc[nt], 0, 0, 0);
      if (!ph2) acc[nt] = __builtin_amdgcn_mfma_f32_16x16x32_bf16(al, bh, acc[nt], 0, 0, 0);
      acc[nt] = __builtin_amdgcn_mfma_f32_16x16x32_bf16(ah, bl, acc[nt], 0, 0, 0);
    }
  }

  // epilogue: write out + accumulate BN stats (sum, sumsq) per channel
  int rbase = node0 + (wv << 4) + ((ln >> 4) << 2);
  int colb = ln & 15;
#pragma unroll
  for (int nt = 0; nt < 8; ++nt) {
    int col = nt * 16 + colb;
    float bb = bv[col];
    float s = 0.f, q = 0.f;
#pragma unroll
    for (int r = 0; r < 4; ++r) {
      int n = rbase + r;
      if (n < N_NODES) {
        float v = acc[nt][r] + bb;
        out[(size_t)n * DH + col] = v;
        s += v; q += v * v;
      }
    }
    atomicAdd(&sstat[col], s);
    atomicAdd(&qstat[col], q);
  }
  __syncthreads();
  for (int i = tid; i < DH; i += 256) {
    atomicAdd(&stats[i], sstat[i]);
    atomicAdd(&stats[128 + i], qstat[i]);
  }
}

// BN + ELU -> h16 plane (bf16)
__global__ void k_bnapply(const float* __restrict__ x, const float* __restrict__ stats,
                          const float* __restrict__ g, const float* __restrict__ be,
                          u32* __restrict__ A) {
  int idx = blockIdx.x * 256 + threadIdx.x;
  if (idx >= N_NODES * DH) return;
  int n = idx >> 7, c = idx & 127;
  float mu = stats[c] * (1.0f / N_NODES);
  float var = stats[128 + c] * (1.0f / N_NODES) - mu * mu;
  float y = (x[idx] - mu) * rsqrtf(var + BN_EPS) * g[c] + be[c];
  y = y > 0.f ? y : expm1f(y);
  ((u16*)(A + (size_t)n * AS + 128))[c] = f2bf(y);
}

// ---------------- layer 2 (project-first, dout=2) ----------------
__global__ void k_l2_dense(const u32* __restrict__ A,
                           const float* __restrict__ Wm2, const float* __restrict__ bm2,
                           const float* __restrict__ Wr2, const float* __restrict__ br2,
                           float* __restrict__ val, float* __restrict__ pm) {
  int wave = threadIdx.x >> 6, lane = threadIdx.x & 63;
  int n = blockIdx.x * 4 + wave;
  if (n >= N_NODES) return;
  const u32* ar = A + (size_t)n * AS;
  const u16* h16 = (const u16*)(ar + 128);
  float h0 = bf2f(h16[lane]);
  float h1 = bf2f(h16[lane + 64]);
  float e0 = unpack_hl(ar[192 + lane]);
  float e1 = (lane < DE - 64) ? unpack_hl(ar[256 + lane]) : 0.f;

  float pm0 = h0 * Wm2[lane] + h1 * Wm2[lane + 64];
  float pm1 = h0 * Wm2[FM + lane] + h1 * Wm2[FM + lane + 64];
  float ve0 = e0 * Wm2[DIN + lane] + ((lane < DE - 64) ? e1 * Wm2[DIN + lane + 64] : 0.f);
  float ve1 = e0 * Wm2[FM + DIN + lane] + ((lane < DE - 64) ? e1 * Wm2[FM + DIN + lane + 64] : 0.f);
  float pr0 = h0 * Wr2[lane] + h1 * Wr2[lane + 64];
  float pr1 = h0 * Wr2[DH + lane] + h1 * Wr2[DH + lane + 64];

#pragma unroll
  for (int m = 32; m >= 1; m >>= 1) {
    pm0 += __shfl_xor(pm0, m, 64); pm1 += __shfl_xor(pm1, m, 64);
    ve0 += __shfl_xor(ve0, m, 64); ve1 += __shfl_xor(ve1, m, 64);
    pr0 += __shfl_xor(pr0, m, 64); pr1 += __shfl_xor(pr1, m, 64);
  }
  if (lane == 0) {
    val[n * 2 + 0] = 0.5f * (ve0 + bm2[0]) + pr0 + br2[0];
    val[n * 2 + 1] = 0.5f * (ve1 + bm2[1]) + pr1 + br2[1];
    pm[n * 2 + 0] = pm0;
    pm[n * 2 + 1] = pm1;
  }
}

__global__ void k_agg2(const int* __restrict__ row_ptr, const uint2* __restrict__ er_s,
                       const float* __restrict__ pm, float* __restrict__ val) {
  int n = blockIdx.x * 256 + threadIdx.x;
  if (n >= N_NODES) return;
  float a0 = 0.f, a1 = 0.f;
  int s = row_ptr[n], e = row_ptr[n + 1];
  for (int p = s; p < e; ++p) {
    int c = er_s[p].x & 0xffff;
    a0 += pm[c * 2]; a1 += pm[c * 2 + 1];
  }
  val[n * 2] += 0.5f * a0;
  val[n * 2 + 1] += 0.5f * a1;
}

__global__ void k_bnstats2(const float* __restrict__ val, float* __restrict__ s4) {
  float s0 = 0.f, q0 = 0.f, s1 = 0.f, q1 = 0.f;
  for (int n = blockIdx.x * 256 + threadIdx.x; n < N_NODES; n += gridDim.x * 256) {
    float v0 = val[n * 2], v1 = val[n * 2 + 1];
    s0 += v0; q0 += v0 * v0; s1 += v1; q1 += v1 * v1;
  }
  __shared__ float b[256][4];
  b[threadIdx.x][0] = s0; b[threadIdx.x][1] = q0;
  b[threadIdx.x][2] = s1; b[threadIdx.x][3] = q1;
  __syncthreads();
  for (int off = 128; off >= 1; off >>= 1) {
    if (threadIdx.x < off)
      for (int j = 0; j < 4; ++j) b[threadIdx.x][j] += b[threadIdx.x + off][j];
    __syncthreads();
  }
  if (threadIdx.x == 0)
    for (int j = 0; j < 4; ++j) atomicAdd(&s4[j], b[0][j]);
}

__global__ void k_final(const float* __restrict__ val, const float* __restrict__ s4,
                        const float* __restrict__ g2, const float* __restrict__ be2,
                        float* __restrict__ out) {
  int n = blockIdx.x * 256 + threadIdx.x;
  if (n >= N_NODES) return;
  float mu0 = s4[0] * (1.f / N_NODES), var0 = s4[1] * (1.f / N_NODES) - mu0 * mu0;
  float mu1 = s4[2] * (1.f / N_NODES), var1 = s4[3] * (1.f / N_NODES) - mu1 * mu1;
  float y0 = (val[n * 2] - mu0) * rsqrtf(var0 + BN_EPS) * g2[0] + be2[0];
  float y1 = (val[n * 2 + 1] - mu1) * rsqrtf(var1 + BN_EPS) * g2[1] + be2[1];
  float m = fmaxf(y0, y1);
  float lse = m + __logf(__expf(y0 - m) + __expf(y1 - m));
  out[n * 2] = y0 - lse;
  out[n * 2 + 1] = y1 - lse;
}

// ---------------- launch ----------------
extern "C" void kernel_launch(void* const* d_in, const int* in_sizes, int n_in,
                              void* d_out, int out_size, void* d_ws, size_t ws_size,
                              hipStream_t stream) {
  (void)in_sizes; (void)n_in; (void)out_size; (void)ws_size;
  const float* x        = (const float*)d_in[0];
  const int*   eidx     = (const int*)d_in[1];
  const int*   row      = eidx;
  const int*   col      = eidx + N_EDGES;
  const int*   attr     = (const int*)d_in[2];
  const int*   tim      = (const int*)d_in[3];
  const int*   dire     = (const int*)d_in[4];
  const float* emb_type = (const float*)d_in[5];
  const float* emb_dir  = (const float*)d_in[6];
  const float* w_t      = (const float*)d_in[7];
  const float* b_t      = (const float*)d_in[8];
  const float* Wm[3] = {(const float*)d_in[9],  (const float*)d_in[15], (const float*)d_in[21]};
  const float* bm[3] = {(const float*)d_in[10], (const float*)d_in[16], (const float*)d_in[22]};
  const float* Wr[3] = {(const float*)d_in[11], (const float*)d_in[17], (const float*)d_in[23]};
  const float* br[3] = {(const float*)d_in[12], (const float*)d_in[18], (const float*)d_in[24]};
  const float* g[3]  = {(const float*)d_in[13], (const float*)d_in[19], (const float*)d_in[25]};
  const float* be[3] = {(const float*)d_in[14], (const float*)d_in[20], (const float*)d_in[26]};
  float* out = (float*)d_out;

  // workspace layout (~97 MB)
  char* p = (char*)d_ws;
  u32* A     = (u32*)p;   p += sizeof(u32) * (size_t)N_NODES * AS;    // 64 MB
  float* gout = (float*)p; p += sizeof(float) * (size_t)N_NODES * DH; // 25.6 MB
  uint2* er_s = (uint2*)p; p += sizeof(uint2) * (size_t)N_EDGES;      // 6.4 MB
  u32* WT2[2];
  WT2[0] = (u32*)p; p += sizeof(u32) * DH * WKL;
  WT2[1] = (u32*)p; p += sizeof(u32) * DH * WKL;
  float* bv[2];
  bv[0] = (float*)p; p += sizeof(float) * DH;
  bv[1] = (float*)p; p += sizeof(float) * DH;
  float* val  = (float*)p;  p += sizeof(float) * (size_t)N_NODES * 2;
  float* pmb  = (float*)p;  p += sizeof(float) * (size_t)N_NODES * 2;
  float* stats = (float*)p; p += sizeof(float) * 520;
  int* counts  = (int*)p;   p += sizeof(int) * N_NODES;
  int* cursor  = (int*)p;   p += sizeof(int) * N_NODES;
  int* row_ptr = (int*)p;   p += sizeof(int) * (N_NODES + 1);
  int* incl    = (int*)p;   p += sizeof(int) * N_NODES;
  int* bsum    = (int*)p;   p += sizeof(int) * SCAN_NB;
  int* boff    = (int*)p;   p += sizeof(int) * SCAN_NB;

  const int EB = (N_EDGES + 255) / 256;      // 3125
  const int NB = (N_NODES + 255) / 256;      // 196
  const int AB = (N_NODES + 3) / 4;          // 12500
  const int GB = (N_NODES + 63) / 64;        // 782
  const int XB = (N_NODES * DH + 255) / 256; // 25000
  const int WB = (DH * WKL + 255) / 256;     // 192

  hipMemsetAsync(counts, 0, sizeof(int) * N_NODES, stream);
  hipMemsetAsync(stats, 0, sizeof(float) * 520, stream);

  // CSR
  k_count<<<EB, 256, 0, stream>>>(row, counts);
  k_scan_a<<<SCAN_NB, 256, 0, stream>>>(counts, incl, bsum);
  k_scan_b<<<1, 256, 0, stream>>>(bsum, boff, row_ptr);
  k_scan_c<<<SCAN_NB, 256, 0, stream>>>(incl, counts, boff, row_ptr, cursor);
  k_fill<<<EB, 256, 0, stream>>>(row, col, attr, dire, tim, cursor, er_s);

  // weight prep
  for (int l = 0; l < 2; ++l) {
    k_wprep<<<WB, 256, 0, stream>>>(Wm[l], Wr[l], WT2[l]);
    k_bias<<<1, 128, 0, stream>>>(bm[l], br[l], bv[l]);
  }

  // x -> h16 plane; edge features -> e region (+pad)
  k_conv_x<<<XB, 256, 0, stream>>>(x, A);
  k_aggE<<<N_NODES, 128, 0, stream>>>(row_ptr, er_s, emb_type, emb_dir, w_t, b_t, A);

  // layer 0
  k_aggH<<<AB, 256, 0, stream>>>(row_ptr, er_s, A);
  k_mfma<<<GB, 256, 0, stream>>>(A, WT2[0], bv[0], gout, stats);
  k_bnapply<<<XB, 256, 0, stream>>>(gout, stats, g[0], be[0], A);

  // layer 1
  k_aggH<<<AB, 256, 0, stream>>>(row_ptr, er_s, A);
  k_mfma<<<GB, 256, 0, stream>>>(A, WT2[1], bv[1], gout, stats + 256);
  k_bnapply<<<XB, 256, 0, stream>>>(gout, stats + 256, g[1], be[1], A);

  // layer 2
  k_l2_dense<<<AB, 256, 0, stream>>>(A, Wm[2], bm[2], Wr[2], br[2], val, pmb);
  k_agg2<<<NB, 256, 0, stream>>>(row_ptr, er_s, pmb, val);
  k_bnstats2<<<64, 256, 0, stream>>>(val, stats + 512);
  k_final<<<NB, 256, 0, stream>>>(val, stats + 512, g[2], be[2], out);
}